// Round 3
// baseline (144.918 us; speedup 1.0000x reference)
//
#include <hip/hip_runtime.h>
#include <hip/hip_fp16.h>

// DFMB PSROIAlign — separable weights + fp16 row-line gathers + SORTED rois.
//
// Cost model (fitted R8/R9/R10): gather cost ~ 1 cycle per (instruction x
// distinct 64B line among the wave's 64 lanes) in the VMEM addresser, plus an
// L2-miss latency term. Layout work (R9/R10) bottomed out at 64 distinct
// lines/instr because every lane holds a different ROI. R11 sorts rois by
// quantized (y0,x0,frac,size) so the 16 lanes sharing a bin-group have
// near-identical patches -> distinct lines/instr drops to ~12-20.
//
// Pipeline: prep (fp16 row-lines) ; zero ; key+hist ; scan ; scatter(perm) ;
// main (block b handles sorted rois perm[16b..16b+15], writes out[perm[..]]).
// XCD-chunked block swizzle keeps each XCD's L2 footprint to its y-band.
//
// Row-line layout (R10): 3 phase copies of 64B lines, copy m line g =
// pixels [3g+m .. 3g+m+2] x 10ch fp16 (60B) + 4B pad. Row window at pixel fp
// = one line (m=fp%3, g=fp/3). Column clamp merged into element weights.

#define NC 10
#define NBIN 49
#define FH 34
#define FW 34
#define PLANE (FH * FW)
#define NPIX (NBIN * PLANE)  // 56644
#define GPC 18882            // lines per phase copy
#define RPB 16               // rois per block
#define TSTRIDE 491          // out-tile row stride (odd -> conflict-free flush)
#define NSIDE 14
#define NBUCKET 65536
#define NXCD 8

__global__ __launch_bounds__(256) void prep_kernel(
    const float* __restrict__ ft, unsigned int* __restrict__ ftR)
{
    const int p = blockIdx.x * 256 + threadIdx.x;  // over NPIX+2 (2 zero tail)
    if (p >= NPIX + 2) return;
    unsigned int h2[5];
    if (p < NPIX) {
#pragma unroll
        for (int c = 0; c < 5; ++c) {
            const __half lo = __float2half_rn(ft[(2 * c)     * NPIX + p]);
            const __half hi = __float2half_rn(ft[(2 * c + 1) * NPIX + p]);
            const __half2 hh = __halves2half2(lo, hi);
            h2[c] = *(const unsigned int*)&hh;
        }
    } else {
#pragma unroll
        for (int c = 0; c < 5; ++c) h2[c] = 0u;  // tail: finite zeros
    }
#pragma unroll
    for (int m = 0; m < 3; ++m) {
        if (p >= m) {
            const int t = p - m;
            const int g = t / 3;
            const int j = t - 3 * g;
            if (g < GPC) {
                unsigned int* d = ftR + ((size_t)m * GPC + g) * 16 + j * 5;
#pragma unroll
                for (int c = 0; c < 5; ++c) d[c] = h2[c];
            }
        }
    }
}

// ---- counting sort over 16-bit spatial keys ----
__device__ __forceinline__ unsigned int roi_key(const float* __restrict__ rois, int n)
{
    const float rsw = rois[n * 5 + 1] * 0.125f;
    const float rsh = rois[n * 5 + 2] * 0.125f;
    const float rew = rois[n * 5 + 3] * 0.125f;
    const float reh = rois[n * 5 + 4] * 0.125f;
    float rh = reh - rsh; if (!(rh > 0.1f)) rh = 0.1f;
    float rw = rew - rsw; if (!(rw > 0.1f)) rw = 0.1f;
    const int y0 = min(31, max(0, (int)floorf(rsh)));
    const int x0 = min(31, max(0, (int)floorf(rsw)));
    const int yf = ((int)floorf(rsh * 2.0f)) & 1;
    const int xf = ((int)floorf(rsw * 2.0f)) & 1;
    const int bh = min(3, (int)(rh * (2.0f / 7.0f)));  // bsh*2 quantized
    const int bw = min(3, (int)(rw * (2.0f / 7.0f)));
    return (unsigned int)((((((((y0 << 5) | x0) << 1) | yf) << 1) | xf) << 2 | bh) << 2 | bw);
}

__global__ __launch_bounds__(256) void zero_kernel(unsigned int* __restrict__ cursor)
{
    cursor[blockIdx.x * 256 + threadIdx.x] = 0u;
}

__global__ __launch_bounds__(256) void hist_kernel(
    const float* __restrict__ rois, unsigned int* __restrict__ keys,
    unsigned int* __restrict__ cursor, int N)
{
    const int n = blockIdx.x * 256 + threadIdx.x;
    if (n >= N) return;
    const unsigned int k = roi_key(rois, n);
    keys[n] = k;
    atomicAdd(&cursor[k], 1u);
}

__global__ __launch_bounds__(1024) void scan_kernel(unsigned int* __restrict__ cursor)
{
    __shared__ unsigned int part[1024];
    const int t = threadIdx.x;
    unsigned int s = 0;
    for (int i = 0; i < 64; ++i) s += cursor[t * 64 + i];
    part[t] = s;
    __syncthreads();
    for (int off = 1; off < 1024; off <<= 1) {
        const unsigned int v = (t >= off) ? part[t - off] : 0u;
        __syncthreads();
        part[t] += v;
        __syncthreads();
    }
    unsigned int ex = (t == 0) ? 0u : part[t - 1];
    for (int i = 0; i < 64; ++i) {   // thread owns its 64 slots exclusively
        const unsigned int c = cursor[t * 64 + i];
        cursor[t * 64 + i] = ex;
        ex += c;
    }
}

__global__ __launch_bounds__(256) void scatter_kernel(
    const unsigned int* __restrict__ keys, unsigned int* __restrict__ cursor,
    int* __restrict__ perm, int N)
{
    const int n = blockIdx.x * 256 + threadIdx.x;
    if (n >= N) return;
    const unsigned int pos = atomicAdd(&cursor[keys[n]], 1u);
    perm[pos] = n;
}

__device__ __forceinline__ void fma2(float w, unsigned int u, float& s0, float& s1)
{
    const __half2 h = *(const __half2*)&u;
    s0 = fmaf(w, __half2float(__low2half(h)),  s0);   // -> v_fma_mix_f32
    s1 = fmaf(w, __half2float(__high2half(h)), s1);
}

__global__ __launch_bounds__(256, 4) void main_kernel(
    const float* __restrict__ rois, const unsigned int* __restrict__ ftR,
    const int* __restrict__ perm, const float* __restrict__ ft,
    float* __restrict__ out, int N, int use_t)
{
    __shared__ float sides[NSIDE][RPB][8];  // 7 KB
    __shared__ float tile[RPB][TSTRIDE];    // 31.4 KB

    // XCD-chunked swizzle (bijective, m204): round-robin -> contiguous chunks
    const int nwg = gridDim.x;
    const int q = nwg / NXCD, rr = nwg % NXCD;
    const int xcd = blockIdx.x % NXCD, idx = blockIdx.x / NXCD;
    const int bid = (xcd < rr ? xcd * (q + 1) : rr * (q + 1) + (xcd - rr) * q) + idx;

    const int r = threadIdx.x & (RPB - 1);  // roi slot within block
    const int s = threadIdx.x >> 4;         // slot 0..15
    const int n = bid * RPB + r;
    const bool valid = (n < N);
    const int nn = (use_t && valid) ? perm[n] : n;  // actual roi index

    float rsw = 0.f, rsh = 0.f, rew = 0.f, reh = 0.f;
    if (valid) {
        rsw = rois[nn * 5 + 1] * 0.125f;  // /STRIDE(8), exact pow2
        rsh = rois[nn * 5 + 2] * 0.125f;
        rew = rois[nn * 5 + 3] * 0.125f;
        reh = rois[nn * 5 + 4] * 0.125f;
    }
    // Explicit _rn chain: floor/ceil/compare inputs must bit-match numpy fp32.
    float rheight = __fsub_rn(reh, rsh);
    if (!(rheight > 0.1f)) rheight = 0.1f;
    float rwidth = __fsub_rn(rew, rsw);
    if (!(rwidth > 0.1f)) rwidth = 0.1f;
    const float bsh   = __fdiv_rn(rheight, 7.0f);
    const float bsw   = __fdiv_rn(rwidth, 7.0f);
    const float sub_h = __fdiv_rn(bsh, 4.0f);
    const float sub_w = __fdiv_rn(bsw, 4.0f);

    // ---- phase 1: one axis-side per slot (slots 0..13 active) ----
    if (s < NSIDE) {
        const bool isY = (s < 7);
        const int  k   = isY ? s : s - 7;
        const float st = isY ? rsh : rsw;
        const float bs = isY ? bsh : bsw;
        const float sb = isY ? sub_h : sub_w;
        const float start = floorf(__fadd_rn(st, __fmul_rn((float)k, bs)));

        float A[3] = {0.f, 0.f, 0.f}, B[3] = {0.f, 0.f, 0.f};
        float cnt = 0.f;
        int P0 = 0;
#pragma unroll
        for (int i = 0; i < 4; ++i) {
            const float h = __fadd_rn(start, __fmul_rn((float)i + 0.5f, sb));
            const bool ok = (h > -1.0f) && (h < 34.0f);
            const int p1 = (int)floorf(h);
            const int p2 = (int)ceilf(h);
            const bool v1 = (p1 >= 0) && (p1 < 34);
            const bool v2 = (p2 >= 0) && (p2 < 34);
            const int p1c = min(max(p1, 0), 33);
            const int p2c = min(max(p2, 0), 33);
            const float d = __fsub_rn(h, (float)p1c);  // vs CLIPPED corner
            if (i == 0) P0 = p1c;                      // min (h increasing)
            const int i1 = p1c - P0, i2 = p2c - P0;    // in {0,1,2}
            const float t1 = ok ? (1.0f - d) : 0.0f;
            const float t2 = ok ? d : 0.0f;
            // bad11 = (!x1v || !x2v) && (y1v || y2v): X carries "invalid",
            // Y carries "valid".
            const bool bsel = isY ? (v1 || v2) : ((!v1) || (!v2));
            const float tb = (ok && bsel) ? (1.0f - d) : 0.0f;
            cnt += ok ? 1.0f : 0.0f;
#pragma unroll
            for (int p = 0; p < 3; ++p) {
                A[p] += (i1 == p) ? t1 : 0.0f;
                A[p] += (i2 == p) ? t2 : 0.0f;
                B[p] += (i1 == p) ? tb : 0.0f;
            }
        }
        float* sp = &sides[s][r][0];
        sp[0] = A[0]; sp[1] = A[1]; sp[2] = A[2];
        sp[3] = B[0]; sp[4] = B[1]; sp[5] = B[2];
        sp[6] = cnt;  sp[7] = (float)P0;
    }
    __syncthreads();

    // ---- phase 2: 4 bins/thread; 3 row-lines per bin ----
#pragma unroll
    for (int j = 0; j < 4; ++j) {
        const int bin = j * RPB + s;
        if (valid && bin < NBIN) {
            const int ph = bin / 7;
            const int pw = bin - ph * 7;

            const float4 ya = *(const float4*)&sides[ph][r][0];
            const float4 yb = *(const float4*)&sides[ph][r][4];
            const float4 xa = *(const float4*)&sides[7 + pw][r][0];
            const float4 xb = *(const float4*)&sides[7 + pw][r][4];
            const float AY[3] = {ya.x, ya.y, ya.z};
            const float BY[3] = {ya.w, yb.x, yb.y};
            const float cntY  = yb.z;
            const int   Y0    = (int)yb.w;
            const float AX[3] = {xa.x, xa.y, xa.z};
            const float BX[3] = {xa.w, xb.x, xb.y};
            const float cntX  = xb.z;
            const int   X0    = (int)xb.w;

            const int binbase = bin * PLANE;
            const int rowo[3] = {binbase + Y0 * FW,
                                 binbase + min(Y0 + 1, FH - 1) * FW,
                                 binbase + min(Y0 + 2, FH - 1) * FW};

            float wgt[9];
#pragma unroll
            for (int p = 0; p < 3; ++p)
#pragma unroll
                for (int q2 = 0; q2 < 3; ++q2)
                    wgt[3 * p + q2] = AY[p] * AX[q2] - BY[p] * BX[q2];

            float sum[NC];
#pragma unroll
            for (int c = 0; c < NC; ++c) sum[c] = 0.f;

            if (use_t) {
                const int e = (FW - 1) - X0;  // >= 0; clamp width of row window
                unsigned int rv[3][15];
                float ew[3][3];
#pragma unroll
                for (int p = 0; p < 3; ++p) {
                    const float w0 = wgt[3 * p], w1 = wgt[3 * p + 1], w2 = wgt[3 * p + 2];
                    const float s12 = w1 + w2;
                    ew[p][0] = (e < 1) ? (w0 + s12) : w0;
                    ew[p][1] = (e < 1) ? 0.f : ((e < 2) ? s12 : w1);
                    ew[p][2] = (e < 2) ? 0.f : w2;
                    const bool rnz = (w0 != 0.0f) || (w1 != 0.0f) || (w2 != 0.0f);
                    const int fp = rnz ? (rowo[p] + X0) : binbase;
                    const int g = fp / 3;
                    const int m = fp - 3 * g;
                    const unsigned int* lp = ftR + ((size_t)m * GPC + g) * 16;
                    const uint4 a = *(const uint4*)lp;
                    const uint4 b = *(const uint4*)(lp + 4);
                    const uint4 c4 = *(const uint4*)(lp + 8);
                    const uint4 d4 = *(const uint4*)(lp + 12);
                    rv[p][0]  = a.x;  rv[p][1]  = a.y;  rv[p][2]  = a.z;  rv[p][3]  = a.w;
                    rv[p][4]  = b.x;  rv[p][5]  = b.y;  rv[p][6]  = b.z;  rv[p][7]  = b.w;
                    rv[p][8]  = c4.x; rv[p][9]  = c4.y; rv[p][10] = c4.z; rv[p][11] = c4.w;
                    rv[p][12] = d4.x; rv[p][13] = d4.y; rv[p][14] = d4.z;  // d4.w = pad
                }
#pragma unroll
                for (int p = 0; p < 3; ++p)
#pragma unroll
                    for (int c = 0; c < 5; ++c) {
                        fma2(ew[p][0], rv[p][c],      sum[2 * c], sum[2 * c + 1]);
                        fma2(ew[p][1], rv[p][5 + c],  sum[2 * c], sum[2 * c + 1]);
                        fma2(ew[p][2], rv[p][10 + c], sum[2 * c], sum[2 * c + 1]);
                    }
            } else {
                const int colo[3] = {X0, min(X0 + 1, FW - 1), min(X0 + 2, FW - 1)};
                int off[9];
#pragma unroll
                for (int p = 0; p < 3; ++p)
#pragma unroll
                    for (int q2 = 0; q2 < 3; ++q2)
                        off[3 * p + q2] = (wgt[3 * p + q2] != 0.0f) ? (rowo[p] + colo[q2])
                                                                    : binbase;
#pragma unroll
                for (int k = 0; k < 9; ++k) {
                    const float w = wgt[k];
#pragma unroll
                    for (int c = 0; c < NC; ++c)
                        sum[c] = fmaf(w, ft[c * NPIX + off[k]], sum[c]);
                }
            }

            const float cnt = cntY * cntX;
            const float inv = (cnt > 0.0f) ? __fdiv_rn(1.0f, cnt) : 1.0f;
            float* tp = &tile[r][0];
#pragma unroll
            for (int c = 0; c < NC; ++c) tp[c * NBIN + bin] = sum[c] * inv;
        }
    }

    __syncthreads();

    // Coalesced flush: 16 rois x 490 contiguous floats, scattered by perm.
    const int n0 = bid * RPB;
    for (int i = threadIdx.x; i < RPB * (NC * NBIN); i += 256) {
        const int row = i / (NC * NBIN);
        const int col = i - row * (NC * NBIN);
        const int n2 = n0 + row;
        if (n2 < N) {
            const int nd = use_t ? perm[n2] : n2;  // 16 hot values, L1-resident
            out[(size_t)nd * (NC * NBIN) + col] = tile[row][col];
        }
    }
}

extern "C" void kernel_launch(void* const* d_in, const int* in_sizes, int n_in,
                              void* d_out, int out_size, void* d_ws, size_t ws_size,
                              hipStream_t stream) {
    const float* ft   = (const float*)d_in[0];
    const float* rois = (const float*)d_in[1];
    float* out        = (float*)d_out;
    const int N = in_sizes[1] / 5;

    // ws layout: ftR (3.46MB) | cursor (256KB) | keys (4N) | perm (4N)
    const size_t ftr_bytes = (size_t)3 * GPC * 64;
    const size_t need = ftr_bytes + (size_t)NBUCKET * 4 + (size_t)8 * N;
    const int use_t = (ws_size >= need) ? 1 : 0;
    unsigned int* ftR    = (unsigned int*)d_ws;
    unsigned int* cursor = (unsigned int*)((char*)d_ws + ftr_bytes);
    unsigned int* keys   = cursor + NBUCKET;
    int*          perm   = (int*)(keys + N);

    if (use_t) {
        prep_kernel<<<(NPIX + 2 + 255) / 256, 256, 0, stream>>>(ft, ftR);
        zero_kernel<<<NBUCKET / 256, 256, 0, stream>>>(cursor);
        hist_kernel<<<(N + 255) / 256, 256, 0, stream>>>(rois, keys, cursor, N);
        scan_kernel<<<1, 1024, 0, stream>>>(cursor);
        scatter_kernel<<<(N + 255) / 256, 256, 0, stream>>>(keys, cursor, perm, N);
    }
    main_kernel<<<(N + RPB - 1) / RPB, 256, 0, stream>>>(rois, ftR, perm, ft, out, N, use_t);
}

// Round 4
// 134.831 us; speedup vs baseline: 1.0748x; 1.0748x over previous
//
#include <hip/hip_runtime.h>
#include <hip/hip_fp16.h>

// DFMB PSROIAlign — fp16 row-line gathers + LDS-sorted rois, 3 dispatches.
//
// Cost model (R8-R11): main_kernel is pinned by the VMEM addresser — cost ~
// distinct 64B lines per gather among the wave's 64 lanes. Unsorted, every
// lane is a different ROI -> 64 distinct lines/instr. R11 proved sorting
// collapses this (main dropped below the 44.5us fill floor) but spent ~50us
// on a 4-kernel global counting sort (single-block strided scan over 65536
// buckets + 4 extra launch gaps ~4.5us each).
//
// R12: same sort, near-zero cost. ONE fused pre-kernel: blocks 0..55 pack the
// fp16 row-line table; block 56 sorts all N rois entirely in LDS:
//   16384 buckets = y0(5b) x0(5b) bh-quartile(2b) bw-quartile(2b),
//   u16-packed counts in 8192 u32 (32KB), keys in 32 statically-unrolled
//   registers, hist -> 1024-thread LDS scan -> in-place packed-half
//   atomicAdd scatter (old>>16*(k&1) & 0xffff = position). No global cursor,
//   no keys array, no extra launches.
//
// Row-line layout (R10): 3 phase copies of 64B lines; copy m line g = pixels
// [3g+m..3g+m+2] x 10ch fp16 (60B)+pad. Window at pixel fp = ONE line
// (m=fp%3, g=fp/3). Column clamp merged into element weights (linearity).
// Main: block b takes sorted rois perm[16b..16b+15] (near-identical patches
// -> 16 lanes share ~2-3 lines), writes out[perm[..]] (exact per-roi math,
// sort only changes which thread computes which roi).

#define NC 10
#define NBIN 49
#define FH 34
#define FW 34
#define PLANE (FH * FW)
#define NPIX (NBIN * PLANE)  // 56644
#define GPC 18882            // row-lines per phase copy
#define RPB 16               // rois per block
#define TSTRIDE 491          // out-tile row stride (odd -> conflict-free flush)
#define NSIDE 14
#define NXCD 8
#define PREP_BLOCKS 56       // ceil((NPIX+2)/1024)
#define KBUCKET 16384        // 14-bit key
#define MAXSORTN 32768       // 32 unrolled slots x 1024 threads

// deterministic bucketing key: y0,x0 integer start; bh,bw size quartiles
__device__ __forceinline__ unsigned int roi_key(const float* __restrict__ rois, int n)
{
    const float rsw = rois[n * 5 + 1] * 0.125f;
    const float rsh = rois[n * 5 + 2] * 0.125f;
    const float rew = rois[n * 5 + 3] * 0.125f;
    const float reh = rois[n * 5 + 4] * 0.125f;
    float rh = reh - rsh; if (!(rh > 0.1f)) rh = 0.1f;
    float rw = rew - rsw; if (!(rw > 0.1f)) rw = 0.1f;
    const int y0 = min(31, max(0, (int)floorf(rsh)));
    const int x0 = min(31, max(0, (int)floorf(rsw)));
    const int bh = min(3, (int)(rh * (4.0f / 9.0f)));  // rheight in [0.1,9]
    const int bw = min(3, (int)(rw * (4.0f / 9.0f)));
    return (unsigned int)(((((y0 << 5) | x0) << 2 | bh) << 2) | bw);
}

__global__ __launch_bounds__(1024) void prep_sort_kernel(
    const float* __restrict__ ft, unsigned int* __restrict__ ftR,
    const float* __restrict__ rois, int* __restrict__ perm, int N)
{
    if (blockIdx.x < PREP_BLOCKS) {
        // ---- fp16 row-line pack (over NPIX+2 pixels; 2 zero tail pixels) ----
        const int p = blockIdx.x * 1024 + threadIdx.x;
        if (p >= NPIX + 2) return;
        unsigned int h2[5];
        if (p < NPIX) {
#pragma unroll
            for (int c = 0; c < 5; ++c) {
                const __half lo = __float2half_rn(ft[(2 * c)     * NPIX + p]);
                const __half hi = __float2half_rn(ft[(2 * c + 1) * NPIX + p]);
                const __half2 hh = __halves2half2(lo, hi);
                h2[c] = *(const unsigned int*)&hh;
            }
        } else {
#pragma unroll
            for (int c = 0; c < 5; ++c) h2[c] = 0u;  // tail: finite zeros
        }
        // pixel p -> copy m (m<=p), line g=(p-m)/3, slot j=(p-m)%3
#pragma unroll
        for (int m = 0; m < 3; ++m) {
            if (p >= m) {
                const int t = p - m;
                const int g = t / 3;
                const int j = t - 3 * g;
                if (g < GPC) {
                    unsigned int* d = ftR + ((size_t)m * GPC + g) * 16 + j * 5;
#pragma unroll
                    for (int c = 0; c < 5; ++c) d[c] = h2[c];
                }
            }
        }
        return;
    }

    // ---- single-block LDS counting sort (block PREP_BLOCKS) ----
    __shared__ unsigned int cnt32[KBUCKET / 2];  // u16-packed counts, 32 KB
    __shared__ unsigned int part[1024];          // scan partials, 4 KB
    const int t = threadIdx.x;

    for (int i = t; i < KBUCKET / 2; i += 1024) cnt32[i] = 0u;
    __syncthreads();

    // pass 1: keys -> regs (static unroll, rule #20), histogram in LDS
    unsigned short kreg[32];
#pragma unroll
    for (int i = 0; i < 32; ++i) {
        const int n = i * 1024 + t;  // consecutive t -> consecutive n (coalesced)
        unsigned int k = 0u;
        if (n < N) {
            k = roi_key(rois, n);
            atomicAdd(&cnt32[k >> 1], (k & 1) ? 0x10000u : 1u);
        }
        kreg[i] = (unsigned short)k;
    }
    __syncthreads();

    // scan: thread t owns u16 buckets [16t,16t+16) = words [8t,8t+8)
    unsigned int tot = 0u;
#pragma unroll
    for (int w = 0; w < 8; ++w) {
        const unsigned int v = cnt32[8 * t + w];
        tot += (v & 0xffffu) + (v >> 16);
    }
    part[t] = tot;
    __syncthreads();
    for (int off = 1; off < 1024; off <<= 1) {
        const unsigned int v = (t >= off) ? part[t - off] : 0u;
        __syncthreads();
        part[t] += v;
        __syncthreads();
    }
    unsigned int base = (t == 0) ? 0u : part[t - 1];
#pragma unroll
    for (int w = 0; w < 8; ++w) {   // in-place: counts -> exclusive bases
        const unsigned int v = cnt32[8 * t + w];
        const unsigned int lo = v & 0xffffu, hi = v >> 16;
        cnt32[8 * t + w] = base | ((base + lo) << 16);
        base += lo + hi;
    }
    __syncthreads();

    // pass 2: scatter; packed-half atomicAdd returns base+rank in our half
    // (halves independent: base+count <= N < 65536, no cross-half carry)
#pragma unroll
    for (int i = 0; i < 32; ++i) {
        const int n = i * 1024 + t;
        if (n < N) {
            const unsigned int k = kreg[i];
            const unsigned int old = atomicAdd(&cnt32[k >> 1], (k & 1) ? 0x10000u : 1u);
            const unsigned int pos = (old >> ((k & 1) * 16)) & 0xffffu;
            perm[pos] = n;
        }
    }
}

__device__ __forceinline__ void fma2(float w, unsigned int u, float& s0, float& s1)
{
    const __half2 h = *(const __half2*)&u;
    s0 = fmaf(w, __half2float(__low2half(h)),  s0);   // -> v_fma_mix_f32
    s1 = fmaf(w, __half2float(__high2half(h)), s1);
}

__global__ __launch_bounds__(256, 4) void main_kernel(
    const float* __restrict__ rois, const unsigned int* __restrict__ ftR,
    const int* __restrict__ perm, const float* __restrict__ ft,
    float* __restrict__ out, int N, int use_t)
{
    __shared__ float sides[NSIDE][RPB][8];  // 7 KB
    __shared__ float tile[RPB][TSTRIDE];    // 31.4 KB

    // XCD-chunked swizzle (bijective): sorted order -> contiguous y-band/XCD
    const int nwg = gridDim.x;
    const int q = nwg / NXCD, rr = nwg % NXCD;
    const int xcd = blockIdx.x % NXCD, idx = blockIdx.x / NXCD;
    const int bid = (xcd < rr ? xcd * (q + 1) : rr * (q + 1) + (xcd - rr) * q) + idx;

    const int r = threadIdx.x & (RPB - 1);  // roi slot within block
    const int s = threadIdx.x >> 4;         // slot 0..15
    const int n = bid * RPB + r;
    const bool valid = (n < N);
    const int nn = (use_t && valid) ? perm[n] : n;  // actual roi index

    float rsw = 0.f, rsh = 0.f, rew = 0.f, reh = 0.f;
    if (valid) {
        rsw = rois[nn * 5 + 1] * 0.125f;  // /STRIDE(8), exact pow2
        rsh = rois[nn * 5 + 2] * 0.125f;
        rew = rois[nn * 5 + 3] * 0.125f;
        reh = rois[nn * 5 + 4] * 0.125f;
    }
    // Explicit _rn chain: floor/ceil/compare inputs must bit-match numpy fp32.
    float rheight = __fsub_rn(reh, rsh);
    if (!(rheight > 0.1f)) rheight = 0.1f;
    float rwidth = __fsub_rn(rew, rsw);
    if (!(rwidth > 0.1f)) rwidth = 0.1f;
    const float bsh   = __fdiv_rn(rheight, 7.0f);
    const float bsw   = __fdiv_rn(rwidth, 7.0f);
    const float sub_h = __fdiv_rn(bsh, 4.0f);
    const float sub_w = __fdiv_rn(bsw, 4.0f);

    // ---- phase 1: one axis-side per slot (slots 0..13 active) ----
    if (s < NSIDE) {
        const bool isY = (s < 7);
        const int  k   = isY ? s : s - 7;
        const float st = isY ? rsh : rsw;
        const float bs = isY ? bsh : bsw;
        const float sb = isY ? sub_h : sub_w;
        const float start = floorf(__fadd_rn(st, __fmul_rn((float)k, bs)));

        float A[3] = {0.f, 0.f, 0.f}, B[3] = {0.f, 0.f, 0.f};
        float cnt = 0.f;
        int P0 = 0;
#pragma unroll
        for (int i = 0; i < 4; ++i) {
            const float h = __fadd_rn(start, __fmul_rn((float)i + 0.5f, sb));
            const bool ok = (h > -1.0f) && (h < 34.0f);
            const int p1 = (int)floorf(h);
            const int p2 = (int)ceilf(h);
            const bool v1 = (p1 >= 0) && (p1 < 34);
            const bool v2 = (p2 >= 0) && (p2 < 34);
            const int p1c = min(max(p1, 0), 33);
            const int p2c = min(max(p2, 0), 33);
            const float d = __fsub_rn(h, (float)p1c);  // vs CLIPPED corner
            if (i == 0) P0 = p1c;                      // min (h increasing)
            const int i1 = p1c - P0, i2 = p2c - P0;    // in {0,1,2}
            const float t1 = ok ? (1.0f - d) : 0.0f;
            const float t2 = ok ? d : 0.0f;
            // bad11 = (!x1v || !x2v) && (y1v || y2v): X carries "invalid",
            // Y carries "valid".
            const bool bsel = isY ? (v1 || v2) : ((!v1) || (!v2));
            const float tb = (ok && bsel) ? (1.0f - d) : 0.0f;
            cnt += ok ? 1.0f : 0.0f;
#pragma unroll
            for (int p = 0; p < 3; ++p) {
                A[p] += (i1 == p) ? t1 : 0.0f;
                A[p] += (i2 == p) ? t2 : 0.0f;
                B[p] += (i1 == p) ? tb : 0.0f;
            }
        }
        float* sp = &sides[s][r][0];
        sp[0] = A[0]; sp[1] = A[1]; sp[2] = A[2];
        sp[3] = B[0]; sp[4] = B[1]; sp[5] = B[2];
        sp[6] = cnt;  sp[7] = (float)P0;
    }
    __syncthreads();

    // ---- phase 2: 4 bins/thread; 3 row-lines per bin ----
#pragma unroll
    for (int j = 0; j < 4; ++j) {
        const int bin = j * RPB + s;
        if (valid && bin < NBIN) {
            const int ph = bin / 7;
            const int pw = bin - ph * 7;

            const float4 ya = *(const float4*)&sides[ph][r][0];
            const float4 yb = *(const float4*)&sides[ph][r][4];
            const float4 xa = *(const float4*)&sides[7 + pw][r][0];
            const float4 xb = *(const float4*)&sides[7 + pw][r][4];
            const float AY[3] = {ya.x, ya.y, ya.z};
            const float BY[3] = {ya.w, yb.x, yb.y};
            const float cntY  = yb.z;
            const int   Y0    = (int)yb.w;
            const float AX[3] = {xa.x, xa.y, xa.z};
            const float BX[3] = {xa.w, xb.x, xb.y};
            const float cntX  = xb.z;
            const int   X0    = (int)xb.w;

            const int binbase = bin * PLANE;
            const int rowo[3] = {binbase + Y0 * FW,
                                 binbase + min(Y0 + 1, FH - 1) * FW,
                                 binbase + min(Y0 + 2, FH - 1) * FW};

            float wgt[9];
#pragma unroll
            for (int p = 0; p < 3; ++p)
#pragma unroll
                for (int q2 = 0; q2 < 3; ++q2)
                    wgt[3 * p + q2] = AY[p] * AX[q2] - BY[p] * BX[q2];

            float sum[NC];
#pragma unroll
            for (int c = 0; c < NC; ++c) sum[c] = 0.f;

            if (use_t) {
                const int e = (FW - 1) - X0;  // >= 0; clamp width of row window
                unsigned int rv[3][15];
                float ew[3][3];
#pragma unroll
                for (int p = 0; p < 3; ++p) {
                    const float w0 = wgt[3 * p], w1 = wgt[3 * p + 1], w2 = wgt[3 * p + 2];
                    const float s12 = w1 + w2;
                    ew[p][0] = (e < 1) ? (w0 + s12) : w0;
                    ew[p][1] = (e < 1) ? 0.f : ((e < 2) ? s12 : w1);
                    ew[p][2] = (e < 2) ? 0.f : w2;
                    const bool rnz = (w0 != 0.0f) || (w1 != 0.0f) || (w2 != 0.0f);
                    const int fp = rnz ? (rowo[p] + X0) : binbase;
                    const int g = fp / 3;
                    const int m = fp - 3 * g;
                    const unsigned int* lp = ftR + ((size_t)m * GPC + g) * 16;
                    const uint4 a = *(const uint4*)lp;
                    const uint4 b = *(const uint4*)(lp + 4);
                    const uint4 c4 = *(const uint4*)(lp + 8);
                    const uint4 d4 = *(const uint4*)(lp + 12);
                    rv[p][0]  = a.x;  rv[p][1]  = a.y;  rv[p][2]  = a.z;  rv[p][3]  = a.w;
                    rv[p][4]  = b.x;  rv[p][5]  = b.y;  rv[p][6]  = b.z;  rv[p][7]  = b.w;
                    rv[p][8]  = c4.x; rv[p][9]  = c4.y; rv[p][10] = c4.z; rv[p][11] = c4.w;
                    rv[p][12] = d4.x; rv[p][13] = d4.y; rv[p][14] = d4.z;  // d4.w = pad
                }
#pragma unroll
                for (int p = 0; p < 3; ++p)
#pragma unroll
                    for (int c = 0; c < 5; ++c) {
                        fma2(ew[p][0], rv[p][c],      sum[2 * c], sum[2 * c + 1]);
                        fma2(ew[p][1], rv[p][5 + c],  sum[2 * c], sum[2 * c + 1]);
                        fma2(ew[p][2], rv[p][10 + c], sum[2 * c], sum[2 * c + 1]);
                    }
            } else {
                const int colo[3] = {X0, min(X0 + 1, FW - 1), min(X0 + 2, FW - 1)};
                int off[9];
#pragma unroll
                for (int p = 0; p < 3; ++p)
#pragma unroll
                    for (int q2 = 0; q2 < 3; ++q2)
                        off[3 * p + q2] = (wgt[3 * p + q2] != 0.0f) ? (rowo[p] + colo[q2])
                                                                    : binbase;
#pragma unroll
                for (int k = 0; k < 9; ++k) {
                    const float w = wgt[k];
#pragma unroll
                    for (int c = 0; c < NC; ++c)
                        sum[c] = fmaf(w, ft[c * NPIX + off[k]], sum[c]);
                }
            }

            const float cnt = cntY * cntX;
            const float inv = (cnt > 0.0f) ? __fdiv_rn(1.0f, cnt) : 1.0f;
            float* tp = &tile[r][0];
#pragma unroll
            for (int c = 0; c < NC; ++c) tp[c * NBIN + bin] = sum[c] * inv;
        }
    }

    __syncthreads();

    // Coalesced flush: 16 rois x 490 contiguous floats, scattered by perm.
    const int n0 = bid * RPB;
    for (int i = threadIdx.x; i < RPB * (NC * NBIN); i += 256) {
        const int row = i / (NC * NBIN);
        const int col = i - row * (NC * NBIN);
        const int n2 = n0 + row;
        if (n2 < N) {
            const int nd = use_t ? perm[n2] : n2;  // 16 hot values, L1-resident
            out[(size_t)nd * (NC * NBIN) + col] = tile[row][col];
        }
    }
}

extern "C" void kernel_launch(void* const* d_in, const int* in_sizes, int n_in,
                              void* d_out, int out_size, void* d_ws, size_t ws_size,
                              hipStream_t stream) {
    const float* ft   = (const float*)d_in[0];
    const float* rois = (const float*)d_in[1];
    float* out        = (float*)d_out;
    const int N = in_sizes[1] / 5;

    // ws layout: ftR (3 copies x GPC x 64B = 3,625,344 B) | perm (4N)
    const size_t ftr_bytes = (size_t)3 * GPC * 64;
    const size_t need = ftr_bytes + (size_t)4 * N;
    const int use_t = (ws_size >= need && N <= MAXSORTN) ? 1 : 0;
    unsigned int* ftR = (unsigned int*)d_ws;
    int*          perm = (int*)((char*)d_ws + ftr_bytes);

    if (use_t) {
        prep_sort_kernel<<<PREP_BLOCKS + 1, 1024, 0, stream>>>(ft, ftR, rois, perm, N);
    }
    main_kernel<<<(N + RPB - 1) / RPB, 256, 0, stream>>>(rois, ftR, perm, ft, out, N, use_t);
}

// Round 6
// 122.137 us; speedup vs baseline: 1.1865x; 1.1039x over previous
//
#include <hip/hip_runtime.h>
#include <hip/hip_fp16.h>

// DFMB PSROIAlign — fp16 row-line gathers + PARALLEL-sorted rois.
//
// Cost model (R8-R12): main_kernel is pinned by the VMEM addresser — cost ~
// distinct 64B lines per gather instruction among the wave's 64 lanes.
// Unsorted every lane is a different ROI -> 64 distinct lines/instr ->
// main 46.3us (R9). Sorting rois by quantized (y0,x0,size) collapses this to
// ~12-16 lines/instr -> main ~33us (R11/R12 ledger), but R11 spent ~50us on
// a serial 65536-strided scan + 4 launch gaps, and R12 spent ~40us on a
// single-block LDS sort (one CU tail while 255 idle).
//
// R13/R14: same sort, all components parallel and ~2us each. R13 used
// hipMemsetAsync for the cursor zero and the container died before pytest —
// suspected graph-capture tripwire (rigor.md bans host-side stream ops in
// kernel_launch); R14 replaces it with a 16-block zero_kernel. Pipeline:
//   zero      (16 blocks, contiguous 64KB cursor)
//   prep+hist (56 pixel blocks || 30 roi-key blocks, global atomics)
//   scan      (1 block x 1024 thr, contiguous words, trivial)
//   scatter   (30 blocks, atomicAdd cursor -> perm)
//   main      (UNCHANGED from R12 — verified twice)
//
// Row-line layout (R10): 3 phase copies of 64B lines; copy m line g = pixels
// [3g+m..3g+m+2] x 10ch fp16 (60B)+pad. Window at pixel fp = ONE line
// (m=fp%3, g=fp/3). Column clamp merged into element weights (linearity).
// Main: block b takes sorted rois perm[16b..16b+15] (similar patches -> wave
// lanes share lines), writes out[perm[..]] (exact per-roi math; sort only
// changes which thread computes which roi).

#define NC 10
#define NBIN 49
#define FH 34
#define FW 34
#define PLANE (FH * FW)
#define NPIX (NBIN * PLANE)  // 56644
#define GPC 18882            // row-lines per phase copy
#define RPB 16               // rois per block
#define TSTRIDE 491          // out-tile row stride (odd -> conflict-free flush)
#define NSIDE 14
#define NXCD 8
#define PREP_BLOCKS 56       // ceil((NPIX+2)/1024)
#define KBUCKET 16384        // 14-bit key: y0(5) x0(5) bh(2) bw(2)

// deterministic bucketing key: y0,x0 integer start; bh,bw size quartiles
__device__ __forceinline__ unsigned int roi_key(const float* __restrict__ rois, int n)
{
    const float rsw = rois[n * 5 + 1] * 0.125f;
    const float rsh = rois[n * 5 + 2] * 0.125f;
    const float rew = rois[n * 5 + 3] * 0.125f;
    const float reh = rois[n * 5 + 4] * 0.125f;
    float rh = reh - rsh; if (!(rh > 0.1f)) rh = 0.1f;
    float rw = rew - rsw; if (!(rw > 0.1f)) rw = 0.1f;
    const int y0 = min(31, max(0, (int)floorf(rsh)));
    const int x0 = min(31, max(0, (int)floorf(rsw)));
    const int bh = min(3, (int)(rh * (4.0f / 9.0f)));  // rheight in (0.1,9]
    const int bw = min(3, (int)(rw * (4.0f / 9.0f)));
    return (unsigned int)(((((y0 << 5) | x0) << 2 | bh) << 2) | bw);
}

__global__ __launch_bounds__(1024) void zero_kernel(unsigned int* __restrict__ cursor)
{
    cursor[blockIdx.x * 1024 + threadIdx.x] = 0u;  // 16 blocks x 1024 = KBUCKET
}

__global__ __launch_bounds__(1024) void prep_hist_kernel(
    const float* __restrict__ ft, unsigned int* __restrict__ ftR,
    const float* __restrict__ rois, unsigned int* __restrict__ keys,
    unsigned int* __restrict__ cursor, int N)
{
    if (blockIdx.x >= PREP_BLOCKS) {
        // ---- roi key + global histogram (parallel across CUs) ----
        const int n = (blockIdx.x - PREP_BLOCKS) * 1024 + threadIdx.x;
        if (n < N) {
            const unsigned int k = roi_key(rois, n);
            keys[n] = k;
            atomicAdd(&cursor[k], 1u);
        }
        return;
    }

    // ---- fp16 row-line pack (over NPIX+2 pixels; 2 zero tail pixels) ----
    const int p = blockIdx.x * 1024 + threadIdx.x;
    if (p >= NPIX + 2) return;
    unsigned int h2[5];
    if (p < NPIX) {
#pragma unroll
        for (int c = 0; c < 5; ++c) {
            const __half lo = __float2half_rn(ft[(2 * c)     * NPIX + p]);
            const __half hi = __float2half_rn(ft[(2 * c + 1) * NPIX + p]);
            const __half2 hh = __halves2half2(lo, hi);
            h2[c] = *(const unsigned int*)&hh;
        }
    } else {
#pragma unroll
        for (int c = 0; c < 5; ++c) h2[c] = 0u;  // tail: finite zeros
    }
    // pixel p -> copy m (m<=p), line g=(p-m)/3, slot j=(p-m)%3
#pragma unroll
    for (int m = 0; m < 3; ++m) {
        if (p >= m) {
            const int t = p - m;
            const int g = t / 3;
            const int j = t - 3 * g;
            if (g < GPC) {
                unsigned int* d = ftR + ((size_t)m * GPC + g) * 16 + j * 5;
#pragma unroll
                for (int c = 0; c < 5; ++c) d[c] = h2[c];
            }
        }
    }
}

__global__ __launch_bounds__(1024) void scan_kernel(unsigned int* __restrict__ cursor)
{
    __shared__ unsigned int part[1024];
    const int t = threadIdx.x;
    unsigned int c[16];         // static-indexed -> registers (rule #20)
    unsigned int s = 0;
#pragma unroll
    for (int i = 0; i < 16; ++i) { c[i] = cursor[t * 16 + i]; s += c[i]; }
    part[t] = s;
    __syncthreads();
    for (int off = 1; off < 1024; off <<= 1) {
        const unsigned int v = (t >= off) ? part[t - off] : 0u;
        __syncthreads();
        part[t] += v;
        __syncthreads();
    }
    unsigned int base = (t == 0) ? 0u : part[t - 1];
#pragma unroll
    for (int i = 0; i < 16; ++i) { cursor[t * 16 + i] = base; base += c[i]; }
}

__global__ __launch_bounds__(1024) void scatter_kernel(
    const unsigned int* __restrict__ keys, unsigned int* __restrict__ cursor,
    int* __restrict__ perm, int N)
{
    const int n = blockIdx.x * 1024 + threadIdx.x;
    if (n >= N) return;
    const unsigned int pos = atomicAdd(&cursor[keys[n]], 1u);
    perm[pos] = n;
}

__device__ __forceinline__ void fma2(float w, unsigned int u, float& s0, float& s1)
{
    const __half2 h = *(const __half2*)&u;
    s0 = fmaf(w, __half2float(__low2half(h)),  s0);   // -> v_fma_mix_f32
    s1 = fmaf(w, __half2float(__high2half(h)), s1);
}

__global__ __launch_bounds__(256, 4) void main_kernel(
    const float* __restrict__ rois, const unsigned int* __restrict__ ftR,
    const int* __restrict__ perm, const float* __restrict__ ft,
    float* __restrict__ out, int N, int use_t)
{
    __shared__ float sides[NSIDE][RPB][8];  // 7 KB
    __shared__ float tile[RPB][TSTRIDE];    // 31.4 KB

    // XCD-chunked swizzle (bijective): sorted order -> contiguous y-band/XCD
    const int nwg = gridDim.x;
    const int q = nwg / NXCD, rr = nwg % NXCD;
    const int xcd = blockIdx.x % NXCD, idx = blockIdx.x / NXCD;
    const int bid = (xcd < rr ? xcd * (q + 1) : rr * (q + 1) + (xcd - rr) * q) + idx;

    const int r = threadIdx.x & (RPB - 1);  // roi slot within block
    const int s = threadIdx.x >> 4;         // slot 0..15
    const int n = bid * RPB + r;
    const bool valid = (n < N);
    const int nn = (use_t && valid) ? perm[n] : n;  // actual roi index

    float rsw = 0.f, rsh = 0.f, rew = 0.f, reh = 0.f;
    if (valid) {
        rsw = rois[nn * 5 + 1] * 0.125f;  // /STRIDE(8), exact pow2
        rsh = rois[nn * 5 + 2] * 0.125f;
        rew = rois[nn * 5 + 3] * 0.125f;
        reh = rois[nn * 5 + 4] * 0.125f;
    }
    // Explicit _rn chain: floor/ceil/compare inputs must bit-match numpy fp32.
    float rheight = __fsub_rn(reh, rsh);
    if (!(rheight > 0.1f)) rheight = 0.1f;
    float rwidth = __fsub_rn(rew, rsw);
    if (!(rwidth > 0.1f)) rwidth = 0.1f;
    const float bsh   = __fdiv_rn(rheight, 7.0f);
    const float bsw   = __fdiv_rn(rwidth, 7.0f);
    const float sub_h = __fdiv_rn(bsh, 4.0f);
    const float sub_w = __fdiv_rn(bsw, 4.0f);

    // ---- phase 1: one axis-side per slot (slots 0..13 active) ----
    if (s < NSIDE) {
        const bool isY = (s < 7);
        const int  k   = isY ? s : s - 7;
        const float st = isY ? rsh : rsw;
        const float bs = isY ? bsh : bsw;
        const float sb = isY ? sub_h : sub_w;
        const float start = floorf(__fadd_rn(st, __fmul_rn((float)k, bs)));

        float A[3] = {0.f, 0.f, 0.f}, B[3] = {0.f, 0.f, 0.f};
        float cnt = 0.f;
        int P0 = 0;
#pragma unroll
        for (int i = 0; i < 4; ++i) {
            const float h = __fadd_rn(start, __fmul_rn((float)i + 0.5f, sb));
            const bool ok = (h > -1.0f) && (h < 34.0f);
            const int p1 = (int)floorf(h);
            const int p2 = (int)ceilf(h);
            const bool v1 = (p1 >= 0) && (p1 < 34);
            const bool v2 = (p2 >= 0) && (p2 < 34);
            const int p1c = min(max(p1, 0), 33);
            const int p2c = min(max(p2, 0), 33);
            const float d = __fsub_rn(h, (float)p1c);  // vs CLIPPED corner
            if (i == 0) P0 = p1c;                      // min (h increasing)
            const int i1 = p1c - P0, i2 = p2c - P0;    // in {0,1,2}
            const float t1 = ok ? (1.0f - d) : 0.0f;
            const float t2 = ok ? d : 0.0f;
            // bad11 = (!x1v || !x2v) && (y1v || y2v): X carries "invalid",
            // Y carries "valid".
            const bool bsel = isY ? (v1 || v2) : ((!v1) || (!v2));
            const float tb = (ok && bsel) ? (1.0f - d) : 0.0f;
            cnt += ok ? 1.0f : 0.0f;
#pragma unroll
            for (int p = 0; p < 3; ++p) {
                A[p] += (i1 == p) ? t1 : 0.0f;
                A[p] += (i2 == p) ? t2 : 0.0f;
                B[p] += (i1 == p) ? tb : 0.0f;
            }
        }
        float* sp = &sides[s][r][0];
        sp[0] = A[0]; sp[1] = A[1]; sp[2] = A[2];
        sp[3] = B[0]; sp[4] = B[1]; sp[5] = B[2];
        sp[6] = cnt;  sp[7] = (float)P0;
    }
    __syncthreads();

    // ---- phase 2: 4 bins/thread; 3 row-lines per bin ----
#pragma unroll
    for (int j = 0; j < 4; ++j) {
        const int bin = j * RPB + s;
        if (valid && bin < NBIN) {
            const int ph = bin / 7;
            const int pw = bin - ph * 7;

            const float4 ya = *(const float4*)&sides[ph][r][0];
            const float4 yb = *(const float4*)&sides[ph][r][4];
            const float4 xa = *(const float4*)&sides[7 + pw][r][0];
            const float4 xb = *(const float4*)&sides[7 + pw][r][4];
            const float AY[3] = {ya.x, ya.y, ya.z};
            const float BY[3] = {ya.w, yb.x, yb.y};
            const float cntY  = yb.z;
            const int   Y0    = (int)yb.w;
            const float AX[3] = {xa.x, xa.y, xa.z};
            const float BX[3] = {xa.w, xb.x, xb.y};
            const float cntX  = xb.z;
            const int   X0    = (int)xb.w;

            const int binbase = bin * PLANE;
            const int rowo[3] = {binbase + Y0 * FW,
                                 binbase + min(Y0 + 1, FH - 1) * FW,
                                 binbase + min(Y0 + 2, FH - 1) * FW};

            float wgt[9];
#pragma unroll
            for (int p = 0; p < 3; ++p)
#pragma unroll
                for (int q2 = 0; q2 < 3; ++q2)
                    wgt[3 * p + q2] = AY[p] * AX[q2] - BY[p] * BX[q2];

            float sum[NC];
#pragma unroll
            for (int c = 0; c < NC; ++c) sum[c] = 0.f;

            if (use_t) {
                const int e = (FW - 1) - X0;  // >= 0; clamp width of row window
                unsigned int rv[3][15];
                float ew[3][3];
#pragma unroll
                for (int p = 0; p < 3; ++p) {
                    const float w0 = wgt[3 * p], w1 = wgt[3 * p + 1], w2 = wgt[3 * p + 2];
                    const float s12 = w1 + w2;
                    ew[p][0] = (e < 1) ? (w0 + s12) : w0;
                    ew[p][1] = (e < 1) ? 0.f : ((e < 2) ? s12 : w1);
                    ew[p][2] = (e < 2) ? 0.f : w2;
                    const bool rnz = (w0 != 0.0f) || (w1 != 0.0f) || (w2 != 0.0f);
                    const int fp = rnz ? (rowo[p] + X0) : binbase;
                    const int g = fp / 3;
                    const int m = fp - 3 * g;
                    const unsigned int* lp = ftR + ((size_t)m * GPC + g) * 16;
                    const uint4 a = *(const uint4*)lp;
                    const uint4 b = *(const uint4*)(lp + 4);
                    const uint4 c4 = *(const uint4*)(lp + 8);
                    const uint4 d4 = *(const uint4*)(lp + 12);
                    rv[p][0]  = a.x;  rv[p][1]  = a.y;  rv[p][2]  = a.z;  rv[p][3]  = a.w;
                    rv[p][4]  = b.x;  rv[p][5]  = b.y;  rv[p][6]  = b.z;  rv[p][7]  = b.w;
                    rv[p][8]  = c4.x; rv[p][9]  = c4.y; rv[p][10] = c4.z; rv[p][11] = c4.w;
                    rv[p][12] = d4.x; rv[p][13] = d4.y; rv[p][14] = d4.z;  // d4.w = pad
                }
#pragma unroll
                for (int p = 0; p < 3; ++p)
#pragma unroll
                    for (int c = 0; c < 5; ++c) {
                        fma2(ew[p][0], rv[p][c],      sum[2 * c], sum[2 * c + 1]);
                        fma2(ew[p][1], rv[p][5 + c],  sum[2 * c], sum[2 * c + 1]);
                        fma2(ew[p][2], rv[p][10 + c], sum[2 * c], sum[2 * c + 1]);
                    }
            } else {
                const int colo[3] = {X0, min(X0 + 1, FW - 1), min(X0 + 2, FW - 1)};
                int off[9];
#pragma unroll
                for (int p = 0; p < 3; ++p)
#pragma unroll
                    for (int q2 = 0; q2 < 3; ++q2)
                        off[3 * p + q2] = (wgt[3 * p + q2] != 0.0f) ? (rowo[p] + colo[q2])
                                                                    : binbase;
#pragma unroll
                for (int k = 0; k < 9; ++k) {
                    const float w = wgt[k];
#pragma unroll
                    for (int c = 0; c < NC; ++c)
                        sum[c] = fmaf(w, ft[c * NPIX + off[k]], sum[c]);
                }
            }

            const float cnt = cntY * cntX;
            const float inv = (cnt > 0.0f) ? __fdiv_rn(1.0f, cnt) : 1.0f;
            float* tp = &tile[r][0];
#pragma unroll
            for (int c = 0; c < NC; ++c) tp[c * NBIN + bin] = sum[c] * inv;
        }
    }

    __syncthreads();

    // Coalesced flush: 16 rois x 490 contiguous floats, scattered by perm.
    const int n0 = bid * RPB;
    for (int i = threadIdx.x; i < RPB * (NC * NBIN); i += 256) {
        const int row = i / (NC * NBIN);
        const int col = i - row * (NC * NBIN);
        const int n2 = n0 + row;
        if (n2 < N) {
            const int nd = use_t ? perm[n2] : n2;  // 16 hot values, L1-resident
            out[(size_t)nd * (NC * NBIN) + col] = tile[row][col];
        }
    }
}

extern "C" void kernel_launch(void* const* d_in, const int* in_sizes, int n_in,
                              void* d_out, int out_size, void* d_ws, size_t ws_size,
                              hipStream_t stream) {
    const float* ft   = (const float*)d_in[0];
    const float* rois = (const float*)d_in[1];
    float* out        = (float*)d_out;
    const int N = in_sizes[1] / 5;

    // ws layout: ftR (3 x GPC x 64B = 3,625,344 B) | cursor (64KB) | keys | perm
    const size_t ftr_bytes = (size_t)3 * GPC * 64;
    const size_t need = ftr_bytes + (size_t)KBUCKET * 4 + (size_t)8 * N;
    const int use_t = (ws_size >= need) ? 1 : 0;
    unsigned int* ftR    = (unsigned int*)d_ws;
    unsigned int* cursor = (unsigned int*)((char*)d_ws + ftr_bytes);
    unsigned int* keys   = cursor + KBUCKET;
    int*          perm   = (int*)(keys + N);

    if (use_t) {
        const int hb = (N + 1023) / 1024;
        zero_kernel<<<KBUCKET / 1024, 1024, 0, stream>>>(cursor);
        prep_hist_kernel<<<PREP_BLOCKS + hb, 1024, 0, stream>>>(ft, ftR, rois, keys, cursor, N);
        scan_kernel<<<1, 1024, 0, stream>>>(cursor);
        scatter_kernel<<<hb, 1024, 0, stream>>>(keys, cursor, perm, N);
    }
    main_kernel<<<(N + RPB - 1) / RPB, 256, 0, stream>>>(rois, ftR, perm, ft, out, N, use_t);
}